// Round 13
// baseline (1571.119 us; speedup 1.0000x reference)
//
#include <hip/hip_runtime.h>

#define B_ 4
#define T_ 4096
#define C_ 1024
#define H_ 128

typedef __attribute__((ext_vector_type(8))) __bf16 bf16x8;
typedef __attribute__((ext_vector_type(8))) unsigned short u16x8;
typedef __attribute__((ext_vector_type(4))) float f32x4;
typedef __attribute__((ext_vector_type(4))) unsigned int u32x4;

__device__ __forceinline__ unsigned short f2bf(float f) {
  unsigned int u = __float_as_uint(f);
  return (unsigned short)((u + 0x7FFFu + ((u >> 16) & 1u)) >> 16);
}
__device__ __forceinline__ float bf2f(unsigned short h) {
  return __uint_as_float((unsigned)h << 16);
}
__device__ __forceinline__ bf16x8 ldb8(const unsigned short* p) {
  return *(const bf16x8*)(const void*)p;
}
// async global->LDS DMA: 16B/lane, LDS dest = wave-uniform base + lane*16
__device__ __forceinline__ void async16(void* lds, const void* g) {
  __builtin_amdgcn_global_load_lds(
      (const __attribute__((address_space(1))) unsigned int*)g,
      (__attribute__((address_space(3))) unsigned int*)lds, 16, 0, 0);
}
__device__ __forceinline__ void split8a(const float* f, bf16x8& hi, bf16x8& lo) {
  u16x8 h, l;
#pragma unroll
  for (int j = 0; j < 8; j++) {
    h[j] = f2bf(f[j]);
    l[j] = f2bf(f[j] - bf2f(h[j]));
  }
  hi = __builtin_bit_cast(bf16x8, h);
  lo = __builtin_bit_cast(bf16x8, l);
}
#define VMC(n) asm volatile("s_waitcnt vmcnt(" #n ")" ::: "memory")

// Fragment-ordered K/V global layouts (per batch, elem offsets):
//   K(t,h): kt=t>>6 n=(t>>4)&3 lk=t&15 kk=h>>5 qk=(h>>3)&3 e=h&7
//           off = ((kt*16+n*4+kk)*64 + qk*16+lk)*8 + e
//   V(t,h): kt=t>>6 ks=(t>>5)&1 qv=(t>>3)&3 j=t&7 nv=h>>4 lv=h&15
//           off = ((kt*16+ks*8+nv)*64 + qv*16+lv)*8 + j
// => a 32-row KV chunk kt32 is elems [kt32*4096, kt32*4096+4096): CONTIGUOUS.

// ---------------------------------------------------------------------------
// Kernel 1: W [C][H] fp32 -> Wthi/Wtlo [.][H][C] bf16, transpose + split,
// 64-elem k-window rotation (c+(h&7))&7 -- EXACT R0-R4 version (qkv v1 pair).
// ---------------------------------------------------------------------------
__global__ void wt_k(const float* __restrict__ Wq, const float* __restrict__ Wk,
                     const float* __restrict__ Wv, unsigned short* __restrict__ Whi,
                     unsigned short* __restrict__ Wlo) {
  __shared__ float tile[32][33];
  int m = blockIdx.z;
  const float* W = (m == 0) ? Wq : ((m == 1) ? Wk : Wv);
  int c0 = blockIdx.x * 32, h0 = blockIdx.y * 32;
  int tx = threadIdx.x, ty = threadIdx.y;  // 32 x 8
#pragma unroll
  for (int i = 0; i < 4; i++)
    tile[ty + 8 * i][tx] = W[(size_t)(c0 + ty + 8 * i) * H_ + h0 + tx];
  __syncthreads();
  size_t base = (size_t)m * H_ * C_;
#pragma unroll
  for (int i = 0; i < 4; i++) {
    float f = tile[tx][ty + 8 * i];
    unsigned short hi = f2bf(f);
    int h = h0 + ty + 8 * i;
    int kg = c0 + tx;
    int w0 = kg >> 6, c = (kg >> 3) & 7, e = kg & 7;
    size_t idx = base + (size_t)h * C_ + w0 * 64 + ((c + (h & 7)) & 7) * 8 + e;
    Whi[idx] = hi;
    if (m < 2) Wlo[idx] = f2bf(f - bf2f(hi));
  }
}

// ---------------------------------------------------------------------------
// Kernel 2: fused QKV projection, BK=64 -- EXACT R0-R4 version.
// ---------------------------------------------------------------------------
__global__ __launch_bounds__(256, 3) void qkv_k(
    const float* __restrict__ x, const unsigned short* __restrict__ Whi,
    const unsigned short* __restrict__ Wlo, unsigned short* __restrict__ Qhi,
    unsigned short* __restrict__ Qlo, unsigned short* __restrict__ Khf,
    unsigned short* __restrict__ Klf, unsigned short* __restrict__ Vf) {
  int m = blockIdx.x % 3;
  int r0 = (blockIdx.x / 3) * 64;
  __shared__ __align__(16) float sx[64 * 64];            // 16 KB
  __shared__ __align__(16) unsigned short swh[128 * 64]; // 16 KB
  __shared__ __align__(16) unsigned short swl[128 * 64]; // 16 KB
  int tid = threadIdx.x;
  int lane = tid & 63, wave = tid >> 6;
  int l15 = lane & 15, quad = lane >> 4;
  const unsigned short* Wmh = Whi + (size_t)m * H_ * C_;
  const unsigned short* Wml = Wlo + (size_t)m * H_ * C_;
  f32x4 acc[8];
#pragma unroll
  for (int n = 0; n < 8; n++) acc[n] = (f32x4){0.f, 0.f, 0.f, 0.f};

  for (int k0 = 0; k0 < C_; k0 += 64) {
    __syncthreads();  // prior iter's LDS reads done
#pragma unroll
    for (int i = 0; i < 4; i++) {
      int s = (wave * 4 + i) * 64 + lane;
      {  // x: LDS slot (tr,p) <- x[r0+tr][k0 + ((p-tr)&15)*4]  (rotated gather)
        int tr = s >> 4, p = s & 15;
        async16((unsigned short*)sx + (size_t)(wave * 4 + i) * 512,
                x + (size_t)(r0 + tr) * C_ + k0 + ((p - tr) & 15) * 4);
      }
      {  // W: flat copy (global already rotated by wt_k)
        int hr = s >> 3, p = s & 7;
        async16(swh + (size_t)(wave * 4 + i) * 512,
                Wmh + (size_t)hr * C_ + k0 + p * 8);
        if (m < 2)
          async16(swl + (size_t)(wave * 4 + i) * 512,
                  Wml + (size_t)hr * C_ + k0 + p * 8);
      }
    }
    __syncthreads();  // barrier drains vmcnt -> staging visible
#pragma unroll
    for (int kk = 0; kk < 2; kk++) {
      float xa[8];
#pragma unroll
      for (int half = 0; half < 2; half++) {
        int p = (kk * 8 + quad * 2 + half + l15) & 15;
        *(f32x4*)&xa[half * 4] =
            *(const f32x4*)(const void*)(sx + (wave * 16 + l15) * 64 + p * 4);
      }
      bf16x8 ahi, alo;
      split8a(xa, ahi, alo);
      if (m < 2) {
#pragma unroll
        for (int n = 0; n < 8; n++) {
          int p = (kk * 4 + quad + l15) & 7;
          bf16x8 bhi = ldb8(swh + (n * 16 + l15) * 64 + p * 8);
          bf16x8 blo = ldb8(swl + (n * 16 + l15) * 64 + p * 8);
          acc[n] = __builtin_amdgcn_mfma_f32_16x16x32_bf16(ahi, bhi, acc[n], 0, 0, 0);
          acc[n] = __builtin_amdgcn_mfma_f32_16x16x32_bf16(alo, bhi, acc[n], 0, 0, 0);
          acc[n] = __builtin_amdgcn_mfma_f32_16x16x32_bf16(ahi, blo, acc[n], 0, 0, 0);
        }
      } else {
#pragma unroll
        for (int n = 0; n < 8; n++) {
          int p = (kk * 4 + quad + l15) & 7;
          bf16x8 bhi = ldb8(swh + (n * 16 + l15) * 64 + p * 8);
          acc[n] = __builtin_amdgcn_mfma_f32_16x16x32_bf16(ahi, bhi, acc[n], 0, 0, 0);
        }
      }
    }
  }
  // epilogue: C-layout row = quad*4+r, col = n8*16+l15
  int ob = r0 + wave * 16 + quad * 4;
  if (m == 0) {  // Q: linear hi/lo
#pragma unroll
    for (int n8 = 0; n8 < 8; n8++)
#pragma unroll
      for (int r = 0; r < 4; r++) {
        float f = acc[n8][r];
        unsigned short hi = f2bf(f);
        size_t idx = (size_t)(ob + r) * H_ + n8 * 16 + l15;
        Qhi[idx] = hi;
        Qlo[idx] = f2bf(f - bf2f(hi));
      }
  } else if (m == 1) {  // K: fragment order hi/lo
#pragma unroll
    for (int n8 = 0; n8 < 8; n8++)
#pragma unroll
      for (int r = 0; r < 4; r++) {
        int gr = ob + r;
        int bb = gr >> 12, t = gr & (T_ - 1);
        int kt = t >> 6, tr = t & 63, nf = tr >> 4, lk = tr & 15;
        int h = n8 * 16 + l15;
        int kkf = h >> 5, qk = (h >> 3) & 3, e = h & 7;
        size_t idx = (size_t)bb * T_ * H_ +
                     (size_t)((kt * 16 + nf * 4 + kkf) * 64 + qk * 16 + lk) * 8 + e;
        float f = acc[n8][r];
        unsigned short hi = f2bf(f);
        Khf[idx] = hi;
        Klf[idx] = f2bf(f - bf2f(hi));
      }
  } else {  // V: fragment order
#pragma unroll
    for (int n8 = 0; n8 < 8; n8++)
#pragma unroll
      for (int r = 0; r < 4; r++) {
        int gr = ob + r;
        int bb = gr >> 12, t = gr & (T_ - 1);
        int kt = t >> 6, ks = (t >> 5) & 1, qv = (t >> 3) & 3, jj = t & 7;
        size_t idx = (size_t)bb * T_ * H_ +
                     (size_t)((kt * 16 + ks * 8 + n8) * 64 + qv * 16 + l15) * 8 + jj;
        Vf[idx] = f2bf(acc[n8][r]);
      }
  }
}

// ---------------------------------------------------------------------------
// Swapped-QK softmax for one 16-row tile -- EXACT flash6 version.
// (flash7's conditional rescale spilled o[] -> reverted; flash8's fused
// combine serialized on __threadfence L2 writebacks -> reverted.)
// ---------------------------------------------------------------------------
__device__ __forceinline__ bf16x8 sm_tile(f32x4* s, float& mr, float& lr,
                                          f32x4* o, int lane) {
  int l15 = lane & 15, quad = lane >> 4;
  float mx = fmaxf(fmaxf(fmaxf(s[0][0], s[0][1]), fmaxf(s[0][2], s[0][3])),
                   fmaxf(fmaxf(s[1][0], s[1][1]), fmaxf(s[1][2], s[1][3])));
  mx = fmaxf(mx, __shfl_xor(mx, 16));
  mx = fmaxf(mx, __shfl_xor(mx, 32));
  float mi = fmaxf(mr, mx);
  float al = __expf(mr - mi);
  mr = mi;
#pragma unroll
  for (int n16 = 0; n16 < 2; n16++)
#pragma unroll
    for (int r = 0; r < 4; r++) s[n16][r] = __expf(s[n16][r] - mi);
  float sum = ((s[0][0] + s[0][1]) + (s[0][2] + s[0][3])) +
              ((s[1][0] + s[1][1]) + (s[1][2] + s[1][3]));
  sum += __shfl_xor(sum, 16);
  sum += __shfl_xor(sum, 32);
  lr = lr * al + sum;
  float alo[4];
#pragma unroll
  for (int r = 0; r < 4; r++) alo[r] = __shfl(al, quad * 4 + r);
#pragma unroll
  for (int nv = 0; nv < 8; nv++)
#pragma unroll
    for (int r = 0; r < 4; r++) o[nv][r] *= alo[r];
  unsigned W[2][2];
#pragma unroll
  for (int n16 = 0; n16 < 2; n16++)
#pragma unroll
    for (int j = 0; j < 2; j++)
      W[n16][j] = (unsigned)f2bf(s[n16][2 * j]) |
                  ((unsigned)f2bf(s[n16][2 * j + 1]) << 16);
  int base = ((lane >> 4) & 1) * 32 + l15;
  unsigned A[4];
#pragma unroll
  for (int a = 0; a < 4; a++) {
    int src = base + (a >> 1) * 16;
    unsigned lo = (unsigned)__shfl((int)W[0][a & 1], src);
    unsigned hi = (unsigned)__shfl((int)W[1][a & 1], src);
    A[a] = (lane & 32) ? hi : lo;
  }
  u32x4 aw = (u32x4){A[0], A[1], A[2], A[3]};
  return __builtin_bit_cast(bf16x8, aw);
}

// ---------------------------------------------------------------------------
// Kernel 3: flash attention v6 (PROVEN 72.2us R9 body, byte-identical loop)
// with ONE change: partials stored as BF16 (halves opart write traffic
// 67->34MB and comb read traffic 134->67MB; mlpart m/l stay f32).
// ---------------------------------------------------------------------------
__global__ __launch_bounds__(256, 2) void flash6_k(
    const unsigned short* __restrict__ Qhi, const unsigned short* __restrict__ Qlo,
    const unsigned short* __restrict__ Khf, const unsigned short* __restrict__ Klf,
    const unsigned short* __restrict__ Vf, unsigned short* __restrict__ opart,
    float2* __restrict__ mlpart) {
  __shared__ __align__(16) unsigned short skh[2][4096];  // 16 KB Khi dbuf
  __shared__ __align__(16) unsigned short skl[2][4096];  // 16 KB Klo dbuf
  __shared__ __align__(16) unsigned short sv[2][4096];   // 16 KB V   dbuf
  int tid = threadIdx.x;
  int wave = tid >> 6, lane = tid & 63;
  int l15 = lane & 15, quad = lane >> 4;

  int n = blockIdx.x;  // 0..1023
  int k = n >> 8, h = (n >> 5) & 7, g = n & 31;
  int p = (k == 0) ? (31 - h) : ((k == 1) ? (16 + h) : ((k == 2) ? (15 - h) : h));
  int sp = g >> 2, b = g & 3;  // XCD (n&7) sees only batch b = n&3
  int q0 = p << 7;
  int NC = 4 * (p + 1);  // total 32-row chunks for this q-tile
  int qq = NC >> 3, rr = NC & 7;
  int ktB = sp * qq + (sp < rr ? sp : rr);
  int nt = qq + (sp < rr ? 1 : 0);
  size_t boff = (size_t)b * T_ * H_;
  const unsigned short* Khb = Khf + boff;
  const unsigned short* Klb = Klf + boff;
  const unsigned short* Vb = Vf + boff;

  bf16x8 qh0[4], ql0[4], qh1[4], ql1[4];
  {
    const unsigned short* qrh =
        Qhi + boff + (size_t)(q0 + wave * 32 + l15) * H_ + quad * 8;
    const unsigned short* qrl =
        Qlo + boff + (size_t)(q0 + wave * 32 + l15) * H_ + quad * 8;
#pragma unroll
    for (int kk = 0; kk < 4; kk++) {
      qh0[kk] = ldb8(qrh + kk * 32);
      ql0[kk] = ldb8(qrl + kk * 32);
      qh1[kk] = ldb8(qrh + 16 * H_ + kk * 32);
      ql1[kk] = ldb8(qrl + 16 * H_ + kk * 32);
    }
  }
  f32x4 o0[8], o1[8];
#pragma unroll
  for (int nn = 0; nn < 8; nn++) {
    o0[nn] = (f32x4){0.f, 0.f, 0.f, 0.f};
    o1[nn] = (f32x4){0.f, 0.f, 0.f, 0.f};
  }
  float mr0 = -1e30f, mr1 = -1e30f, lr0 = 0.f, lr1 = 0.f;

  int rmin = q0 + wave * 32;
  int ch = wave * 2;

#define STAGE(kt32_, d_)                                                        \
  {                                                                             \
    size_t gbase = (size_t)(kt32_)*4096 + (size_t)ch * 512 + (size_t)lane * 8;  \
    async16(&skh[d_][ch * 512], Khb + gbase);                                   \
    async16(&skh[d_][(ch + 1) * 512], Khb + gbase + 512);                       \
    async16(&skl[d_][ch * 512], Klb + gbase);                                   \
    async16(&skl[d_][(ch + 1) * 512], Klb + gbase + 512);                       \
    async16(&sv[d_][ch * 512], Vb + gbase);                                     \
    async16(&sv[d_][(ch + 1) * 512], Vb + gbase + 512);                         \
  }

  if (nt > 0) {
    STAGE(ktB, 0);
    int cur = 0;
    for (int it = 0; it < nt; ++it) {
      int kt32 = ktB + it;
      if (it + 1 < nt) {
        STAGE(kt32 + 1, cur ^ 1);  // issue next tile (6 loads stay in flight)
        VMC(6);                    // current tile done
      } else {
        VMC(0);
      }
      __builtin_amdgcn_s_barrier();  // staging visible to all waves
      int c0k = kt32 << 5;
      bool t1a = (c0k <= rmin + 31);
      bool t0a = (c0k <= rmin + 15);
      if (t1a) {
        f32x4 s0[2], s1[2];
#pragma unroll
        for (int n16 = 0; n16 < 2; ++n16) {
          s0[n16] = (f32x4){0.f, 0.f, 0.f, 0.f};
          s1[n16] = (f32x4){0.f, 0.f, 0.f, 0.f};
        }
        __builtin_amdgcn_s_setprio(1);
#pragma unroll
        for (int n16 = 0; n16 < 2; ++n16) {
          bf16x8 kh[4], kl[4];
#pragma unroll
          for (int kk = 0; kk < 4; kk++) {
            kh[kk] = ldb8(&skh[cur][(n16 * 4 + kk) * 512 + lane * 8]);
            kl[kk] = ldb8(&skl[cur][(n16 * 4 + kk) * 512 + lane * 8]);
          }
#pragma unroll
          for (int kk = 0; kk < 4; kk++) {  // SWAPPED operands: S^T = K x Q
            s1[n16] = __builtin_amdgcn_mfma_f32_16x16x32_bf16(kh[kk], qh1[kk], s1[n16], 0, 0, 0);
            s1[n16] = __builtin_amdgcn_mfma_f32_16x16x32_bf16(kh[kk], ql1[kk], s1[n16], 0, 0, 0);
            s1[n16] = __builtin_amdgcn_mfma_f32_16x16x32_bf16(kl[kk], qh1[kk], s1[n16], 0, 0, 0);
            if (t0a) {
              s0[n16] = __builtin_amdgcn_mfma_f32_16x16x32_bf16(kh[kk], qh0[kk], s0[n16], 0, 0, 0);
              s0[n16] = __builtin_amdgcn_mfma_f32_16x16x32_bf16(kh[kk], ql0[kk], s0[n16], 0, 0, 0);
              s0[n16] = __builtin_amdgcn_mfma_f32_16x16x32_bf16(kl[kk], qh0[kk], s0[n16], 0, 0, 0);
            }
          }
        }
        __builtin_amdgcn_s_setprio(0);
        if (c0k + 31 > rmin + 16) {
          int row1 = rmin + 16 + l15;
#pragma unroll
          for (int n16 = 0; n16 < 2; ++n16)
#pragma unroll
            for (int r = 0; r < 4; r++) {
              int col = c0k + n16 * 16 + quad * 4 + r;
              if (col > row1) s1[n16][r] = -1e30f;
            }
        }
        if (t0a && c0k + 31 > rmin) {
          int row0 = rmin + l15;
#pragma unroll
          for (int n16 = 0; n16 < 2; ++n16)
#pragma unroll
            for (int r = 0; r < 4; r++) {
              int col = c0k + n16 * 16 + quad * 4 + r;
              if (col > row0) s0[n16][r] = -1e30f;
            }
        }
        bf16x8 pa1 = sm_tile(s1, mr1, lr1, o1, lane);
        bf16x8 pa0;
        if (t0a) pa0 = sm_tile(s0, mr0, lr0, o0, lane);
        __builtin_amdgcn_s_setprio(1);
#pragma unroll
        for (int nv = 0; nv < 8; ++nv) {
          bf16x8 vf = ldb8(&sv[cur][nv * 512 + lane * 8]);
          o1[nv] = __builtin_amdgcn_mfma_f32_16x16x32_bf16(pa1, vf, o1[nv], 0, 0, 0);
          if (t0a)
            o0[nv] = __builtin_amdgcn_mfma_f32_16x16x32_bf16(pa0, vf, o0[nv], 0, 0, 0);
        }
        __builtin_amdgcn_s_setprio(0);
      }
      __builtin_amdgcn_s_barrier();  // all waves done reading buf before reuse
      cur ^= 1;
    }
  }
#undef STAGE

  // epilogue: unnormalized partials (BF16) -> slot ((b*32+p)*8+sp)
  size_t slot = (size_t)((b * 32 + p) * 8 + sp);
  size_t obase = slot * (128 * 128);
  size_t mbase = slot * 128;
  int wr0 = wave * 32 + quad * 4;
#pragma unroll
  for (int nn = 0; nn < 8; nn++)
#pragma unroll
    for (int r = 0; r < 4; r++) {
      opart[obase + (size_t)(wr0 + r) * 128 + nn * 16 + l15] = f2bf(o0[nn][r]);
      opart[obase + (size_t)(wr0 + 16 + r) * 128 + nn * 16 + l15] = f2bf(o1[nn][r]);
    }
  if (quad == 0) {
    mlpart[mbase + wave * 32 + l15] = make_float2(mr0, lr0);
    mlpart[mbase + wave * 32 + 16 + l15] = make_float2(mr1, lr1);
  }
}

// ---------------------------------------------------------------------------
// Kernel 4: merge the EIGHT KV-splits (BF16 partials). One thread = 8 cols.
// ---------------------------------------------------------------------------
__global__ __launch_bounds__(256) void comb_k(
    const unsigned short* __restrict__ opart, const float2* __restrict__ mlpart,
    float* __restrict__ out) {
  int gid = blockIdx.x * 256 + threadIdx.x;  // 0 .. B*T*16-1
  int row = gid >> 4;
  int c0 = (gid & 15) << 3;
  int b = row >> 12, t = row & (T_ - 1);
  int p = t >> 7, r = t & 127;
  size_t base = (size_t)(b * 32 + p) * 8;  // (b,p) -> 8 splits
  float2 ml[8];
#pragma unroll
  for (int s = 0; s < 8; s++) ml[s] = mlpart[(base + s) * 128 + r];
  float M = ml[0].x;
#pragma unroll
  for (int s = 1; s < 8; s++) M = fmaxf(M, ml[s].x);
  float w[8], L = 0.f;
#pragma unroll
  for (int s = 0; s < 8; s++) {
    w[s] = __expf(ml[s].x - M);
    L += w[s] * ml[s].y;
  }
  float invL = 1.0f / L;
  float a[8];
#pragma unroll
  for (int j = 0; j < 8; j++) a[j] = 0.f;
#pragma unroll
  for (int s = 0; s < 8; s++) {
    u16x8 v = *(const u16x8*)(const void*)(opart + (base + s) * (128 * 128) +
                                           (size_t)r * 128 + c0);
#pragma unroll
    for (int j = 0; j < 8; j++) a[j] += bf2f(v[j]) * w[s];
  }
  float* op = out + ((size_t)b * T_ + t) * H_ + c0;
  f32x4 r0 = (f32x4){a[0], a[1], a[2], a[3]} * invL;
  f32x4 r1 = (f32x4){a[4], a[5], a[6], a[7]} * invL;
  *(f32x4*)(void*)op = r0;
  *(f32x4*)(void*)(op + 4) = r1;
}

// ---------------------------------------------------------------------------
extern "C" void kernel_launch(void* const* d_in, const int* in_sizes, int n_in,
                              void* d_out, int out_size, void* d_ws, size_t ws_size,
                              hipStream_t stream) {
  const float* x  = (const float*)d_in[0];
  const float* Wq = (const float*)d_in[1];
  const float* Wk = (const float*)d_in[2];
  const float* Wv = (const float*)d_in[3];
  const size_t BTH = (size_t)B_ * T_ * H_;
  unsigned short* Whi = (unsigned short*)d_ws;   // 3*H*C
  unsigned short* Wlo = Whi + 3 * H_ * C_;       // 2*H*C (Q,K only)
  unsigned short* Vf  = Wlo + 2 * H_ * C_;       // BTH
  unsigned short* Qhi = Vf + BTH;
  unsigned short* Qlo = Qhi + BTH;
  unsigned short* Khf = Qlo + BTH;
  unsigned short* Klf = Khf + BTH;
  unsigned short* opart = Klf + BTH;             // 8 splits * BTH bf16 (34MB)
  float2* mlpart = (float2*)(void*)(opart + 8 * BTH);   // 1024 slots * 128
  float* out = (float*)d_out;

  wt_k<<<dim3(32, 4, 3), dim3(32, 8), 0, stream>>>(Wq, Wk, Wv, Whi, Wlo);
  qkv_k<<<3 * (B_ * T_ / 64), 256, 0, stream>>>(x, Whi, Wlo, Qhi, Qlo, Khf, Klf, Vf);
  flash6_k<<<1024, 256, 0, stream>>>(Qhi, Qlo, Khf, Klf, Vf, opart, mlpart);
  comb_k<<<(B_ * T_ * 16) / 256, 256, 0, stream>>>(opart, mlpart, out);
}

// Round 14
// 211.066 us; speedup vs baseline: 7.4437x; 7.4437x over previous
//
#include <hip/hip_runtime.h>

#define B_ 4
#define T_ 4096
#define C_ 1024
#define H_ 128

typedef __attribute__((ext_vector_type(8))) __bf16 bf16x8;
typedef __attribute__((ext_vector_type(8))) unsigned short u16x8;
typedef __attribute__((ext_vector_type(4))) float f32x4;
typedef __attribute__((ext_vector_type(4))) unsigned int u32x4;

__device__ __forceinline__ unsigned short f2bf(float f) {
  unsigned int u = __float_as_uint(f);
  return (unsigned short)((u + 0x7FFFu + ((u >> 16) & 1u)) >> 16);
}
__device__ __forceinline__ float bf2f(unsigned short h) {
  return __uint_as_float((unsigned)h << 16);
}
__device__ __forceinline__ bf16x8 ldb8(const unsigned short* p) {
  return *(const bf16x8*)(const void*)p;
}
// async global->LDS DMA: 16B/lane, LDS dest = wave-uniform base + lane*16
__device__ __forceinline__ void async16(void* lds, const void* g) {
  __builtin_amdgcn_global_load_lds(
      (const __attribute__((address_space(1))) unsigned int*)g,
      (__attribute__((address_space(3))) unsigned int*)lds, 16, 0, 0);
}
__device__ __forceinline__ void split8a(const float* f, bf16x8& hi, bf16x8& lo) {
  u16x8 h, l;
#pragma unroll
  for (int j = 0; j < 8; j++) {
    h[j] = f2bf(f[j]);
    l[j] = f2bf(f[j] - bf2f(h[j]));
  }
  hi = __builtin_bit_cast(bf16x8, h);
  lo = __builtin_bit_cast(bf16x8, l);
}
#define VMC(n) asm volatile("s_waitcnt vmcnt(" #n ")" ::: "memory")

// Fragment-ordered K/V global layouts (per batch, elem offsets):
//   K(t,h): kt=t>>6 n=(t>>4)&3 lk=t&15 kk=h>>5 qk=(h>>3)&3 e=h&7
//           off = ((kt*16+n*4+kk)*64 + qk*16+lk)*8 + e
//   V(t,h): kt=t>>6 ks=(t>>5)&1 qv=(t>>3)&3 j=t&7 nv=h>>4 lv=h&15
//           off = ((kt*16+ks*8+nv)*64 + qv*16+lv)*8 + j
// => a 32-row KV chunk kt32 is elems [kt32*4096, kt32*4096+4096): CONTIGUOUS.
//
// HISTORY (measured): flash7 conditional rescale -> o[] spill (+74MB, 123us);
// flash8 fused combine -> __threadfence L2-writeback serialization (285us);
// flash6-bf16 partials -> 32B partial-line RMW thrash (4.8GB writes, 1489us).
// f32 full-segment partial stores are LOAD-BEARING.  This file = exact R9.

// ---------------------------------------------------------------------------
// Kernel 1: W [C][H] fp32 -> Wthi/Wtlo [.][H][C] bf16, transpose + split,
// 64-elem k-window rotation (c+(h&7))&7 -- EXACT R0-R4 version (qkv v1 pair).
// ---------------------------------------------------------------------------
__global__ void wt_k(const float* __restrict__ Wq, const float* __restrict__ Wk,
                     const float* __restrict__ Wv, unsigned short* __restrict__ Whi,
                     unsigned short* __restrict__ Wlo) {
  __shared__ float tile[32][33];
  int m = blockIdx.z;
  const float* W = (m == 0) ? Wq : ((m == 1) ? Wk : Wv);
  int c0 = blockIdx.x * 32, h0 = blockIdx.y * 32;
  int tx = threadIdx.x, ty = threadIdx.y;  // 32 x 8
#pragma unroll
  for (int i = 0; i < 4; i++)
    tile[ty + 8 * i][tx] = W[(size_t)(c0 + ty + 8 * i) * H_ + h0 + tx];
  __syncthreads();
  size_t base = (size_t)m * H_ * C_;
#pragma unroll
  for (int i = 0; i < 4; i++) {
    float f = tile[tx][ty + 8 * i];
    unsigned short hi = f2bf(f);
    int h = h0 + ty + 8 * i;
    int kg = c0 + tx;
    int w0 = kg >> 6, c = (kg >> 3) & 7, e = kg & 7;
    size_t idx = base + (size_t)h * C_ + w0 * 64 + ((c + (h & 7)) & 7) * 8 + e;
    Whi[idx] = hi;
    if (m < 2) Wlo[idx] = f2bf(f - bf2f(hi));
  }
}

// ---------------------------------------------------------------------------
// Kernel 2: fused QKV projection, BK=64 -- EXACT R0-R4 version.
// ---------------------------------------------------------------------------
__global__ __launch_bounds__(256, 3) void qkv_k(
    const float* __restrict__ x, const unsigned short* __restrict__ Whi,
    const unsigned short* __restrict__ Wlo, unsigned short* __restrict__ Qhi,
    unsigned short* __restrict__ Qlo, unsigned short* __restrict__ Khf,
    unsigned short* __restrict__ Klf, unsigned short* __restrict__ Vf) {
  int m = blockIdx.x % 3;
  int r0 = (blockIdx.x / 3) * 64;
  __shared__ __align__(16) float sx[64 * 64];            // 16 KB
  __shared__ __align__(16) unsigned short swh[128 * 64]; // 16 KB
  __shared__ __align__(16) unsigned short swl[128 * 64]; // 16 KB
  int tid = threadIdx.x;
  int lane = tid & 63, wave = tid >> 6;
  int l15 = lane & 15, quad = lane >> 4;
  const unsigned short* Wmh = Whi + (size_t)m * H_ * C_;
  const unsigned short* Wml = Wlo + (size_t)m * H_ * C_;
  f32x4 acc[8];
#pragma unroll
  for (int n = 0; n < 8; n++) acc[n] = (f32x4){0.f, 0.f, 0.f, 0.f};

  for (int k0 = 0; k0 < C_; k0 += 64) {
    __syncthreads();  // prior iter's LDS reads done
#pragma unroll
    for (int i = 0; i < 4; i++) {
      int s = (wave * 4 + i) * 64 + lane;
      {  // x: LDS slot (tr,p) <- x[r0+tr][k0 + ((p-tr)&15)*4]  (rotated gather)
        int tr = s >> 4, p = s & 15;
        async16((unsigned short*)sx + (size_t)(wave * 4 + i) * 512,
                x + (size_t)(r0 + tr) * C_ + k0 + ((p - tr) & 15) * 4);
      }
      {  // W: flat copy (global already rotated by wt_k)
        int hr = s >> 3, p = s & 7;
        async16(swh + (size_t)(wave * 4 + i) * 512,
                Wmh + (size_t)hr * C_ + k0 + p * 8);
        if (m < 2)
          async16(swl + (size_t)(wave * 4 + i) * 512,
                  Wml + (size_t)hr * C_ + k0 + p * 8);
      }
    }
    __syncthreads();  // barrier drains vmcnt -> staging visible
#pragma unroll
    for (int kk = 0; kk < 2; kk++) {
      float xa[8];
#pragma unroll
      for (int half = 0; half < 2; half++) {
        int p = (kk * 8 + quad * 2 + half + l15) & 15;
        *(f32x4*)&xa[half * 4] =
            *(const f32x4*)(const void*)(sx + (wave * 16 + l15) * 64 + p * 4);
      }
      bf16x8 ahi, alo;
      split8a(xa, ahi, alo);
      if (m < 2) {
#pragma unroll
        for (int n = 0; n < 8; n++) {
          int p = (kk * 4 + quad + l15) & 7;
          bf16x8 bhi = ldb8(swh + (n * 16 + l15) * 64 + p * 8);
          bf16x8 blo = ldb8(swl + (n * 16 + l15) * 64 + p * 8);
          acc[n] = __builtin_amdgcn_mfma_f32_16x16x32_bf16(ahi, bhi, acc[n], 0, 0, 0);
          acc[n] = __builtin_amdgcn_mfma_f32_16x16x32_bf16(alo, bhi, acc[n], 0, 0, 0);
          acc[n] = __builtin_amdgcn_mfma_f32_16x16x32_bf16(ahi, blo, acc[n], 0, 0, 0);
        }
      } else {
#pragma unroll
        for (int n = 0; n < 8; n++) {
          int p = (kk * 4 + quad + l15) & 7;
          bf16x8 bhi = ldb8(swh + (n * 16 + l15) * 64 + p * 8);
          acc[n] = __builtin_amdgcn_mfma_f32_16x16x32_bf16(ahi, bhi, acc[n], 0, 0, 0);
        }
      }
    }
  }
  // epilogue: C-layout row = quad*4+r, col = n8*16+l15
  int ob = r0 + wave * 16 + quad * 4;
  if (m == 0) {  // Q: linear hi/lo
#pragma unroll
    for (int n8 = 0; n8 < 8; n8++)
#pragma unroll
      for (int r = 0; r < 4; r++) {
        float f = acc[n8][r];
        unsigned short hi = f2bf(f);
        size_t idx = (size_t)(ob + r) * H_ + n8 * 16 + l15;
        Qhi[idx] = hi;
        Qlo[idx] = f2bf(f - bf2f(hi));
      }
  } else if (m == 1) {  // K: fragment order hi/lo
#pragma unroll
    for (int n8 = 0; n8 < 8; n8++)
#pragma unroll
      for (int r = 0; r < 4; r++) {
        int gr = ob + r;
        int bb = gr >> 12, t = gr & (T_ - 1);
        int kt = t >> 6, tr = t & 63, nf = tr >> 4, lk = tr & 15;
        int h = n8 * 16 + l15;
        int kkf = h >> 5, qk = (h >> 3) & 3, e = h & 7;
        size_t idx = (size_t)bb * T_ * H_ +
                     (size_t)((kt * 16 + nf * 4 + kkf) * 64 + qk * 16 + lk) * 8 + e;
        float f = acc[n8][r];
        unsigned short hi = f2bf(f);
        Khf[idx] = hi;
        Klf[idx] = f2bf(f - bf2f(hi));
      }
  } else {  // V: fragment order
#pragma unroll
    for (int n8 = 0; n8 < 8; n8++)
#pragma unroll
      for (int r = 0; r < 4; r++) {
        int gr = ob + r;
        int bb = gr >> 12, t = gr & (T_ - 1);
        int kt = t >> 6, ks = (t >> 5) & 1, qv = (t >> 3) & 3, jj = t & 7;
        size_t idx = (size_t)bb * T_ * H_ +
                     (size_t)((kt * 16 + ks * 8 + n8) * 64 + qv * 16 + l15) * 8 + jj;
        Vf[idx] = f2bf(acc[n8][r]);
      }
  }
}

// ---------------------------------------------------------------------------
// Swapped-QK softmax for one 16-row tile -- EXACT flash6/R9 version.
// ---------------------------------------------------------------------------
__device__ __forceinline__ bf16x8 sm_tile(f32x4* s, float& mr, float& lr,
                                          f32x4* o, int lane) {
  int l15 = lane & 15, quad = lane >> 4;
  float mx = fmaxf(fmaxf(fmaxf(s[0][0], s[0][1]), fmaxf(s[0][2], s[0][3])),
                   fmaxf(fmaxf(s[1][0], s[1][1]), fmaxf(s[1][2], s[1][3])));
  mx = fmaxf(mx, __shfl_xor(mx, 16));
  mx = fmaxf(mx, __shfl_xor(mx, 32));
  float mi = fmaxf(mr, mx);
  float al = __expf(mr - mi);
  mr = mi;
#pragma unroll
  for (int n16 = 0; n16 < 2; n16++)
#pragma unroll
    for (int r = 0; r < 4; r++) s[n16][r] = __expf(s[n16][r] - mi);
  float sum = ((s[0][0] + s[0][1]) + (s[0][2] + s[0][3])) +
              ((s[1][0] + s[1][1]) + (s[1][2] + s[1][3]));
  sum += __shfl_xor(sum, 16);
  sum += __shfl_xor(sum, 32);
  lr = lr * al + sum;
  float alo[4];
#pragma unroll
  for (int r = 0; r < 4; r++) alo[r] = __shfl(al, quad * 4 + r);
#pragma unroll
  for (int nv = 0; nv < 8; nv++)
#pragma unroll
    for (int r = 0; r < 4; r++) o[nv][r] *= alo[r];
  unsigned W[2][2];
#pragma unroll
  for (int n16 = 0; n16 < 2; n16++)
#pragma unroll
    for (int j = 0; j < 2; j++)
      W[n16][j] = (unsigned)f2bf(s[n16][2 * j]) |
                  ((unsigned)f2bf(s[n16][2 * j + 1]) << 16);
  int base = ((lane >> 4) & 1) * 32 + l15;
  unsigned A[4];
#pragma unroll
  for (int a = 0; a < 4; a++) {
    int src = base + (a >> 1) * 16;
    unsigned lo = (unsigned)__shfl((int)W[0][a & 1], src);
    unsigned hi = (unsigned)__shfl((int)W[1][a & 1], src);
    A[a] = (lane & 32) ? hi : lo;
  }
  u32x4 aw = (u32x4){A[0], A[1], A[2], A[3]};
  return __builtin_bit_cast(bf16x8, aw);
}

// ---------------------------------------------------------------------------
// Kernel 3: flash attention v6 -- EXACT R9 version (72.2us measured).
// split-KV x8, round-balanced mapping, dbuf KV via global_load_lds,
// counted vmcnt(6), swapped QK^T, in-register P, f32 partials.
// ---------------------------------------------------------------------------
__global__ __launch_bounds__(256, 2) void flash6_k(
    const unsigned short* __restrict__ Qhi, const unsigned short* __restrict__ Qlo,
    const unsigned short* __restrict__ Khf, const unsigned short* __restrict__ Klf,
    const unsigned short* __restrict__ Vf, float* __restrict__ opart,
    float2* __restrict__ mlpart) {
  __shared__ __align__(16) unsigned short skh[2][4096];  // 16 KB Khi dbuf
  __shared__ __align__(16) unsigned short skl[2][4096];  // 16 KB Klo dbuf
  __shared__ __align__(16) unsigned short sv[2][4096];   // 16 KB V   dbuf
  int tid = threadIdx.x;
  int wave = tid >> 6, lane = tid & 63;
  int l15 = lane & 15, quad = lane >> 4;

  int n = blockIdx.x;  // 0..1023
  int k = n >> 8, h = (n >> 5) & 7, g = n & 31;
  int p = (k == 0) ? (31 - h) : ((k == 1) ? (16 + h) : ((k == 2) ? (15 - h) : h));
  int sp = g >> 2, b = g & 3;  // XCD (n&7) sees only batch b = n&3
  int q0 = p << 7;
  int NC = 4 * (p + 1);  // total 32-row chunks for this q-tile
  int qq = NC >> 3, rr = NC & 7;
  int ktB = sp * qq + (sp < rr ? sp : rr);
  int nt = qq + (sp < rr ? 1 : 0);
  size_t boff = (size_t)b * T_ * H_;
  const unsigned short* Khb = Khf + boff;
  const unsigned short* Klb = Klf + boff;
  const unsigned short* Vb = Vf + boff;

  bf16x8 qh0[4], ql0[4], qh1[4], ql1[4];
  {
    const unsigned short* qrh =
        Qhi + boff + (size_t)(q0 + wave * 32 + l15) * H_ + quad * 8;
    const unsigned short* qrl =
        Qlo + boff + (size_t)(q0 + wave * 32 + l15) * H_ + quad * 8;
#pragma unroll
    for (int kk = 0; kk < 4; kk++) {
      qh0[kk] = ldb8(qrh + kk * 32);
      ql0[kk] = ldb8(qrl + kk * 32);
      qh1[kk] = ldb8(qrh + 16 * H_ + kk * 32);
      ql1[kk] = ldb8(qrl + 16 * H_ + kk * 32);
    }
  }
  f32x4 o0[8], o1[8];
#pragma unroll
  for (int nn = 0; nn < 8; nn++) {
    o0[nn] = (f32x4){0.f, 0.f, 0.f, 0.f};
    o1[nn] = (f32x4){0.f, 0.f, 0.f, 0.f};
  }
  float mr0 = -1e30f, mr1 = -1e30f, lr0 = 0.f, lr1 = 0.f;

  int rmin = q0 + wave * 32;
  int ch = wave * 2;

#define STAGE(kt32_, d_)                                                        \
  {                                                                             \
    size_t gbase = (size_t)(kt32_)*4096 + (size_t)ch * 512 + (size_t)lane * 8;  \
    async16(&skh[d_][ch * 512], Khb + gbase);                                   \
    async16(&skh[d_][(ch + 1) * 512], Khb + gbase + 512);                       \
    async16(&skl[d_][ch * 512], Klb + gbase);                                   \
    async16(&skl[d_][(ch + 1) * 512], Klb + gbase + 512);                       \
    async16(&sv[d_][ch * 512], Vb + gbase);                                     \
    async16(&sv[d_][(ch + 1) * 512], Vb + gbase + 512);                         \
  }

  if (nt > 0) {
    STAGE(ktB, 0);
    int cur = 0;
    for (int it = 0; it < nt; ++it) {
      int kt32 = ktB + it;
      if (it + 1 < nt) {
        STAGE(kt32 + 1, cur ^ 1);  // issue next tile (6 loads stay in flight)
        VMC(6);                    // current tile done
      } else {
        VMC(0);
      }
      __builtin_amdgcn_s_barrier();  // staging visible to all waves
      int c0k = kt32 << 5;
      bool t1a = (c0k <= rmin + 31);
      bool t0a = (c0k <= rmin + 15);
      if (t1a) {
        f32x4 s0[2], s1[2];
#pragma unroll
        for (int n16 = 0; n16 < 2; ++n16) {
          s0[n16] = (f32x4){0.f, 0.f, 0.f, 0.f};
          s1[n16] = (f32x4){0.f, 0.f, 0.f, 0.f};
        }
        __builtin_amdgcn_s_setprio(1);
#pragma unroll
        for (int n16 = 0; n16 < 2; ++n16) {
          bf16x8 kh[4], kl[4];
#pragma unroll
          for (int kk = 0; kk < 4; kk++) {
            kh[kk] = ldb8(&skh[cur][(n16 * 4 + kk) * 512 + lane * 8]);
            kl[kk] = ldb8(&skl[cur][(n16 * 4 + kk) * 512 + lane * 8]);
          }
#pragma unroll
          for (int kk = 0; kk < 4; kk++) {  // SWAPPED operands: S^T = K x Q
            s1[n16] = __builtin_amdgcn_mfma_f32_16x16x32_bf16(kh[kk], qh1[kk], s1[n16], 0, 0, 0);
            s1[n16] = __builtin_amdgcn_mfma_f32_16x16x32_bf16(kh[kk], ql1[kk], s1[n16], 0, 0, 0);
            s1[n16] = __builtin_amdgcn_mfma_f32_16x16x32_bf16(kl[kk], qh1[kk], s1[n16], 0, 0, 0);
            if (t0a) {
              s0[n16] = __builtin_amdgcn_mfma_f32_16x16x32_bf16(kh[kk], qh0[kk], s0[n16], 0, 0, 0);
              s0[n16] = __builtin_amdgcn_mfma_f32_16x16x32_bf16(kh[kk], ql0[kk], s0[n16], 0, 0, 0);
              s0[n16] = __builtin_amdgcn_mfma_f32_16x16x32_bf16(kl[kk], qh0[kk], s0[n16], 0, 0, 0);
            }
          }
        }
        __builtin_amdgcn_s_setprio(0);
        if (c0k + 31 > rmin + 16) {
          int row1 = rmin + 16 + l15;
#pragma unroll
          for (int n16 = 0; n16 < 2; ++n16)
#pragma unroll
            for (int r = 0; r < 4; r++) {
              int col = c0k + n16 * 16 + quad * 4 + r;
              if (col > row1) s1[n16][r] = -1e30f;
            }
        }
        if (t0a && c0k + 31 > rmin) {
          int row0 = rmin + l15;
#pragma unroll
          for (int n16 = 0; n16 < 2; ++n16)
#pragma unroll
            for (int r = 0; r < 4; r++) {
              int col = c0k + n16 * 16 + quad * 4 + r;
              if (col > row0) s0[n16][r] = -1e30f;
            }
        }
        bf16x8 pa1 = sm_tile(s1, mr1, lr1, o1, lane);
        bf16x8 pa0;
        if (t0a) pa0 = sm_tile(s0, mr0, lr0, o0, lane);
        __builtin_amdgcn_s_setprio(1);
#pragma unroll
        for (int nv = 0; nv < 8; ++nv) {
          bf16x8 vf = ldb8(&sv[cur][nv * 512 + lane * 8]);
          o1[nv] = __builtin_amdgcn_mfma_f32_16x16x32_bf16(pa1, vf, o1[nv], 0, 0, 0);
          if (t0a)
            o0[nv] = __builtin_amdgcn_mfma_f32_16x16x32_bf16(pa0, vf, o0[nv], 0, 0, 0);
        }
        __builtin_amdgcn_s_setprio(0);
      }
      __builtin_amdgcn_s_barrier();  // all waves done reading buf before reuse
      cur ^= 1;
    }
  }
#undef STAGE

  // epilogue: unnormalized partials -> slot ((b*32+p)*8+sp)
  size_t slot = (size_t)((b * 32 + p) * 8 + sp);
  size_t obase = slot * (128 * 128);
  size_t mbase = slot * 128;
  int wr0 = wave * 32 + quad * 4;
#pragma unroll
  for (int nn = 0; nn < 8; nn++)
#pragma unroll
    for (int r = 0; r < 4; r++) {
      opart[obase + (size_t)(wr0 + r) * 128 + nn * 16 + l15] = o0[nn][r];
      opart[obase + (size_t)(wr0 + 16 + r) * 128 + nn * 16 + l15] = o1[nn][r];
    }
  if (quad == 0) {
    mlpart[mbase + wave * 32 + l15] = make_float2(mr0, lr0);
    mlpart[mbase + wave * 32 + 16 + l15] = make_float2(mr1, lr1);
  }
}

// ---------------------------------------------------------------------------
// Kernel 4: merge the EIGHT KV-splits. One thread = 8 output cols.
// ---------------------------------------------------------------------------
__global__ __launch_bounds__(256) void comb_k(const float* __restrict__ opart,
                                              const float2* __restrict__ mlpart,
                                              float* __restrict__ out) {
  int gid = blockIdx.x * 256 + threadIdx.x;  // 0 .. B*T*16-1
  int row = gid >> 4;
  int c0 = (gid & 15) << 3;
  int b = row >> 12, t = row & (T_ - 1);
  int p = t >> 7, r = t & 127;
  size_t base = (size_t)(b * 32 + p) * 8;  // (b,p) -> 8 splits
  float2 ml[8];
#pragma unroll
  for (int s = 0; s < 8; s++) ml[s] = mlpart[(base + s) * 128 + r];
  float M = ml[0].x;
#pragma unroll
  for (int s = 1; s < 8; s++) M = fmaxf(M, ml[s].x);
  float w[8], L = 0.f;
#pragma unroll
  for (int s = 0; s < 8; s++) {
    w[s] = __expf(ml[s].x - M);
    L += w[s] * ml[s].y;
  }
  float invL = 1.0f / L;
  f32x4 a0 = (f32x4){0.f, 0.f, 0.f, 0.f}, a1 = a0;
#pragma unroll
  for (int s = 0; s < 8; s++) {
    const float* src = opart + (base + s) * (128 * 128) + (size_t)r * 128 + c0;
    a0 += *(const f32x4*)(const void*)src * w[s];
    a1 += *(const f32x4*)(const void*)(src + 4) * w[s];
  }
  float* op = out + ((size_t)b * T_ + t) * H_ + c0;
  *(f32x4*)(void*)op = a0 * invL;
  *(f32x4*)(void*)(op + 4) = a1 * invL;
}

// ---------------------------------------------------------------------------
extern "C" void kernel_launch(void* const* d_in, const int* in_sizes, int n_in,
                              void* d_out, int out_size, void* d_ws, size_t ws_size,
                              hipStream_t stream) {
  const float* x  = (const float*)d_in[0];
  const float* Wq = (const float*)d_in[1];
  const float* Wk = (const float*)d_in[2];
  const float* Wv = (const float*)d_in[3];
  const size_t BTH = (size_t)B_ * T_ * H_;
  unsigned short* Whi = (unsigned short*)d_ws;   // 3*H*C
  unsigned short* Wlo = Whi + 3 * H_ * C_;       // 2*H*C (Q,K only)
  unsigned short* Vf  = Wlo + 2 * H_ * C_;       // BTH
  unsigned short* Qhi = Vf + BTH;
  unsigned short* Qlo = Qhi + BTH;
  unsigned short* Khf = Qlo + BTH;
  unsigned short* Klf = Khf + BTH;
  float* opart = (float*)(void*)(Klf + BTH);     // 8 splits * BTH f32 (67MB)
  float2* mlpart = (float2*)(void*)(opart + 8 * BTH);
  float* out = (float*)d_out;

  wt_k<<<dim3(32, 4, 3), dim3(32, 8), 0, stream>>>(Wq, Wk, Wv, Whi, Wlo);
  qkv_k<<<3 * (B_ * T_ / 64), 256, 0, stream>>>(x, Whi, Wlo, Qhi, Qlo, Khf, Klf, Vf);
  flash6_k<<<1024, 256, 0, stream>>>(Qhi, Qlo, Khf, Klf, Vf, opart, mlpart);
  comb_k<<<(B_ * T_ * 16) / 256, 256, 0, stream>>>(opart, mlpart, out);
}